// Round 9
// baseline (300.616 us; speedup 1.0000x reference)
//
#include <hip/hip_runtime.h>

// OrthoLinear: out[32,8192] = x @ (dequant int4 W)^T + alpha * x @ CSR^T
// R4 analysis: 136us fused with MfmaUtil 2.4 / VALU 10 / HBM 9% => ~85% latency
// stall. R5: (1) 2-deep ping-pong register prefetch in dense K-loop (raise MLP
// to BW saturation), (2) (v,col) prefetch in sparse loop, (3) remove needless
// __syncthreads (reduce buffer is per-wave), (4) coalesced LDS-tiled prep
// transpose (old xTb scatter = 64 lines/wave-store), out-zero folded into prep.
// R6-R9: resubmit unchanged (bench never ran: GPUAcquisitionTimeout).

#define IN_F 8192
#define OUT_F 8192
#define NROW 32
#define KSPLIT 8
#define KSEG (IN_F / KSPLIT)   // 1024
#define CHUNKS (KSEG / 32)     // 32

typedef __attribute__((ext_vector_type(8))) short short8v;
typedef __attribute__((ext_vector_type(4))) float f32x4;

union Frag {
  int4 v;
  unsigned int u[4];
  short8v s;
};

__device__ __forceinline__ unsigned int cvt_pk_bf16(float lo, float hi) {
  unsigned int r;
  asm("v_cvt_pk_bf16_f32 %0, %1, %2" : "=v"(r) : "v"(lo), "v"(hi));
  return r;
}

__device__ __forceinline__ unsigned short f2bf(float f) {
  unsigned int u = __float_as_uint(f);
  u += 0x7FFFu + ((u >> 16) & 1u);  // round-to-nearest-even
  return (unsigned short)(u >> 16);
}

// prep: 128 blocks x 256 thr; block b owns k-range [b*64, +64).
// phase1: coalesced x reads, x_hi/x_lo stores, LDS tile T[k][n] (stride 33).
// phase2: coalesced xTb writes (lane -> contiguous 16B, wave -> 1KB).
// Also zero-inits d_out (poisoned 0xAA by harness before every call).
__global__ __launch_bounds__(256) void prep_kernel(
    const float* __restrict__ x, unsigned short* __restrict__ x_hi,
    unsigned short* __restrict__ x_lo, unsigned short* __restrict__ xTb,
    float* __restrict__ out) {
  __shared__ unsigned short T[64 * 33];
  int tid = threadIdx.x;
  int k0 = blockIdx.x * 64;

  // zero out: 65536 float4 / 128 blocks = 512 per block, 2 per thread
  {
    float4 z = {0.f, 0.f, 0.f, 0.f};
    float4* o4 = (float4*)out;
    o4[blockIdx.x * 512 + tid] = z;
    o4[blockIdx.x * 512 + 256 + tid] = z;
  }

  int kk = tid & 63;   // k within chunk
  int ng = tid >> 6;   // 0..3
#pragma unroll
  for (int p = 0; p < 8; ++p) {
    int n = p * 4 + ng;
    int idx = n * IN_F + k0 + kk;
    float v = x[idx];
    unsigned short h = f2bf(v);
    float hf = __uint_as_float((unsigned int)h << 16);
    unsigned short l = f2bf(v - hf);
    x_hi[idx] = h;
    x_lo[idx] = l;
    T[kk * 33 + n] = h;
  }
  __syncthreads();
  // phase2: thread -> (k = k0 + tid>>2, quarter q = tid&3), pack 8 shorts -> int4
  int kr = tid >> 2, q = tid & 3;
  unsigned int s0 = T[kr * 33 + q * 8 + 0], s1 = T[kr * 33 + q * 8 + 1];
  unsigned int s2 = T[kr * 33 + q * 8 + 2], s3 = T[kr * 33 + q * 8 + 3];
  unsigned int s4 = T[kr * 33 + q * 8 + 4], s5 = T[kr * 33 + q * 8 + 5];
  unsigned int s6 = T[kr * 33 + q * 8 + 6], s7 = T[kr * 33 + q * 8 + 7];
  int4 wv;
  wv.x = (int)(s0 | (s1 << 16));
  wv.y = (int)(s2 | (s3 << 16));
  wv.z = (int)(s4 | (s5 << 16));
  wv.w = (int)(s6 | (s7 << 16));
  ((int4*)xTb)[(size_t)(k0 + kr) * 4 + q] = wv;  // xTb row k = 64B = 4 int4
}

__global__ __launch_bounds__(256) void fused_kernel(
    const int* __restrict__ packed, const float* __restrict__ scales,
    const float* __restrict__ vals, const int* __restrict__ cols,
    const int* __restrict__ rptr, const float* __restrict__ alphap,
    const unsigned short* __restrict__ x_hi,
    const unsigned short* __restrict__ x_lo,
    const unsigned short* __restrict__ xTb, float* __restrict__ out) {
  __shared__ float red[4][64 * 33];  // per-wave transpose-reduce scratch
  int tid = threadIdx.x;
  int lane = tid & 63;
  int w = tid >> 6;
  int og = blockIdx.x >> 3;   // 0..127
  int g = blockIdx.x & 7;     // K-segment
  int lo16 = lane & 15;
  int lhi = lane >> 4;

  // ---------------- dense int4 GEMM, 2-deep ping-pong prefetch ----------------
  int o = og * 64 + w * 16 + lo16;
  int kbeg = g * KSEG;
  const int4* wp = (const int4*)(packed + (size_t)o * (IN_F / 2) + (kbeg >> 1)) + lhi;
  const unsigned short* xh = x_hi + lo16 * IN_F + kbeg + 8 * lhi;
  const unsigned short* xl = x_lo + lo16 * IN_F + kbeg + 8 * lhi;

  f32x4 acc0 = {0.f, 0.f, 0.f, 0.f};
  f32x4 acc1 = {0.f, 0.f, 0.f, 0.f};

  Frag wA, h0A, l0A, h1A, l1A;
  Frag wB, h0B, l0B, h1B, l1B;

#define LOADIN(W_, H0, L0, H1, L1, c)                  \
  W_.v = wp[(c) * 4];                                  \
  H0.v = *(const int4*)(xh + (c) * 32);                \
  L0.v = *(const int4*)(xl + (c) * 32);                \
  H1.v = *(const int4*)(xh + 16 * IN_F + (c) * 32);    \
  L1.v = *(const int4*)(xl + 16 * IN_F + (c) * 32);

#define COMPUTE(W_, H0, L0, H1, L1)                                               \
  {                                                                               \
    Frag b;                                                                       \
    b.u[0] = cvt_pk_bf16((float)(W_.v.x & 15) - 8.0f, (float)(W_.v.x >> 4) - 8.0f); \
    b.u[1] = cvt_pk_bf16((float)(W_.v.y & 15) - 8.0f, (float)(W_.v.y >> 4) - 8.0f); \
    b.u[2] = cvt_pk_bf16((float)(W_.v.z & 15) - 8.0f, (float)(W_.v.z >> 4) - 8.0f); \
    b.u[3] = cvt_pk_bf16((float)(W_.v.w & 15) - 8.0f, (float)(W_.v.w >> 4) - 8.0f); \
    acc0 = __builtin_amdgcn_mfma_f32_16x16x32_bf16(H0.s, b.s, acc0, 0, 0, 0);     \
    acc0 = __builtin_amdgcn_mfma_f32_16x16x32_bf16(L0.s, b.s, acc0, 0, 0, 0);     \
    acc1 = __builtin_amdgcn_mfma_f32_16x16x32_bf16(H1.s, b.s, acc1, 0, 0, 0);     \
    acc1 = __builtin_amdgcn_mfma_f32_16x16x32_bf16(L1.s, b.s, acc1, 0, 0, 0);     \
  }

  LOADIN(wA, h0A, l0A, h1A, l1A, 0)
  for (int c = 0; c < CHUNKS; c += 2) {
    LOADIN(wB, h0B, l0B, h1B, l1B, c + 1)         // c+1 <= 31 always (CHUNKS even)
    COMPUTE(wA, h0A, l0A, h1A, l1A)
    if (c + 2 < CHUNKS) {
      LOADIN(wA, h0A, l0A, h1A, l1A, c + 2)
    }
    COMPUTE(wB, h0B, l0B, h1B, l1B)
  }
#undef LOADIN
#undef COMPUTE

  // C layout: col = lane&15 (= o), row = (lane>>4)*4 + r
  float sc = scales[o];
#pragma unroll
  for (int r = 0; r < 4; ++r) {
    int m = lhi * 4 + r;
    atomicAdd(&out[(size_t)m * OUT_F + o], sc * acc0[r]);
    atomicAdd(&out[(size_t)(m + 16) * OUT_F + o], sc * acc1[r]);
  }

  // ---------------- sparse CSR phase (per-wave, barrier-free) ----------------
  float alpha = alphap[0];
  float* R = red[w];
#pragma unroll 1
  for (int rr = 0; rr < 2; ++rr) {
    int ro = og * 64 + g * 8 + w * 2 + rr;
    int js = rptr[ro], je = rptr[ro + 1];
    float acc[32];
#pragma unroll
    for (int i = 0; i < 32; ++i) acc[i] = 0.f;

    int j = js + lane;
    float vc = 0.f;
    int cc = 0;
    if (j < je) { vc = vals[j]; cc = cols[j]; }
    while (j < je) {
      int jn = j + 64;
      float vn = 0.f;
      int cn = 0;
      if (jn < je) { vn = vals[jn]; cn = cols[jn]; }  // prefetch next (v,col)
      const int4* xp = (const int4*)(xTb + (size_t)cc * NROW);
      int4 q0 = xp[0], q1 = xp[1], q2 = xp[2], q3 = xp[3];
#define UNP(dw, base)                                                          \
  {                                                                            \
    unsigned int ud = (unsigned int)(dw);                                      \
    acc[base] = fmaf(vc, __uint_as_float(ud << 16), acc[base]);                \
    acc[base + 1] = fmaf(vc, __uint_as_float(ud & 0xFFFF0000u), acc[base + 1]); \
  }
      UNP(q0.x, 0) UNP(q0.y, 2) UNP(q0.z, 4) UNP(q0.w, 6)
      UNP(q1.x, 8) UNP(q1.y, 10) UNP(q1.z, 12) UNP(q1.w, 14)
      UNP(q2.x, 16) UNP(q2.y, 18) UNP(q2.z, 20) UNP(q2.w, 22)
      UNP(q3.x, 24) UNP(q3.y, 26) UNP(q3.z, 28) UNP(q3.w, 30)
#undef UNP
      j = jn;
      vc = vn;
      cc = cn;
    }
    // per-wave LDS transpose-reduce, stride 33 (no block barrier needed)
#pragma unroll
    for (int i = 0; i < 32; ++i) R[lane * 33 + i] = acc[i];
    int cidx = lane & 31;
    int h = lane >> 5;
    float sum = 0.f;
#pragma unroll
    for (int r2 = 0; r2 < 32; ++r2) sum += R[(h * 32 + r2) * 33 + cidx];
    sum += __shfl_xor(sum, 32, 64);
    if (lane < 32) atomicAdd(&out[(size_t)lane * OUT_F + ro], alpha * sum);
  }
}

extern "C" void kernel_launch(void* const* d_in, const int* in_sizes, int n_in,
                              void* d_out, int out_size, void* d_ws, size_t ws_size,
                              hipStream_t stream) {
  const float* x = (const float*)d_in[0];
  const int* packed = (const int*)d_in[1];
  const float* scales = (const float*)d_in[2];
  const float* vals = (const float*)d_in[3];
  const int* cols = (const int*)d_in[4];
  const int* rptr = (const int*)d_in[5];
  const float* alphap = (const float*)d_in[6];
  float* out = (float*)d_out;

  unsigned short* x_hi = (unsigned short*)d_ws;                  // 512 KB
  unsigned short* x_lo = x_hi + NROW * IN_F;                     // 512 KB
  unsigned short* xTb = x_lo + NROW * IN_F;                      // 512 KB

  prep_kernel<<<IN_F / 64, 256, 0, stream>>>(x, x_hi, x_lo, xTb, out);
  fused_kernel<<<(OUT_F / 64) * KSPLIT, 256, 0, stream>>>(
      packed, scales, vals, cols, rptr, alphap, x_hi, x_lo, xTb, out);
}